// Round 19
// baseline (482.096 us; speedup 1.0000x reference)
//
#include <hip/hip_runtime.h>
#include <hip/hip_bf16.h>
#include <stdint.h>

// Problem constants
#define NB_B 2048
#define NN   64
#define DD   256
#define HH   1024
#define EE   512
#define HC   128          // H chunk size
#define NCH  (HH/HC)      // 8 chunks

typedef __attribute__((ext_vector_type(16))) float f32x16;   // 32x32 MFMA accumulator
typedef __attribute__((ext_vector_type(8)))  int   int8v;    // 32B f8f6f4 operand (8 VGPRs)

#define W1SCALE 32.0f     // W1 pre-scaled into e4m3 range; undone in pack_h bias-add
#define W2SCALE 32.0f     // W2 pre-scaled into e4m3 range; undone in epilogue

// LDS layout (all-MX, 4-deep Hs ring for produce-2/consume-2 phases):
//   Xs: [64] rows, 272B stride (256 fp8 data + 16 pad), plain row-major (17 KiB)
//   Hs: [64] rows, 144B stride (128 data + 16 pad), 4 buffers  (4 x 9216 B)
//   Bs: b1 copy, 1024 f32                                       (4 KiB)
#define XS_OFF 0
#define XSTRIDE 272
#define HS_OFF 17408
#define HSTRIDE 144
#define HBUF  9216
#define BS_OFF 54272
#define LDS_TOT 58368

// Prep: weights in per-lane K=64 MX fragment order, fp8 e4m3, 32B/lane.
//   w1mx: frag f = ((hc*4 + wh)*4 + kk)*64 + g5*32 + l31:
//       byte j (0..31) = fp8(32*W1[(kk*64 + g5*32 + j)][hc*128 + wh*32 + l31])
//       (8192 frags x 32B = 256 KiB)
//   w2mx: frag f = ((eblk*8 + hc)*2 + kk)*64 + g5*32 + l31:
//       byte j (0..31) = fp8(32*W2[(hc*128 + kk*64 + g5*32 + j)][eblk*32 + l31])
//       (16384 frags x 32B = 512 KiB)
__global__ void prep_weights(const float* __restrict__ W1, const float* __restrict__ W2,
                             int* __restrict__ w1mx, int* __restrict__ w2mx) {
    int g = blockIdx.x * 512 + threadIdx.x;      // 48 blocks * 512 = 24576 exactly
    if (g < 8192) {
        int f   = g;
        int l31 = f & 31;
        int g5  = (f >> 5) & 1;
        int kk  = (f >> 6) & 3;
        int wh  = (f >> 8) & 3;
        int hc  = f >> 10;                        // 0..7
        int h   = hc * 128 + wh * 32 + l31;
        int d0  = kk * 64 + g5 * 32;
        int* dst = w1mx + (size_t)f * 8;
        #pragma unroll
        for (int q = 0; q < 8; ++q) {
            float t0 = W1[(size_t)(d0 + 4 * q + 0) * HH + h] * W1SCALE;
            float t1 = W1[(size_t)(d0 + 4 * q + 1) * HH + h] * W1SCALE;
            float t2 = W1[(size_t)(d0 + 4 * q + 2) * HH + h] * W1SCALE;
            float t3 = W1[(size_t)(d0 + 4 * q + 3) * HH + h] * W1SCALE;
            int pk = __builtin_amdgcn_cvt_pk_fp8_f32(t0, t1, 0, false);
            pk     = __builtin_amdgcn_cvt_pk_fp8_f32(t2, t3, pk, true);
            dst[q] = pk;
        }
    } else {
        int f    = g - 8192;                      // 0..16383
        int l31  = f & 31;
        int g5   = (f >> 5) & 1;
        int kk   = (f >> 6) & 1;
        int hc   = (f >> 7) & 7;
        int eblk = f >> 10;                       // 0..15
        int e    = eblk * 32 + l31;
        int k0   = hc * 128 + kk * 64 + g5 * 32;
        int* dst = w2mx + (size_t)f * 8;
        #pragma unroll
        for (int q = 0; q < 8; ++q) {
            float t0 = W2[(size_t)(k0 + 4 * q + 0) * EE + e] * W2SCALE;
            float t1 = W2[(size_t)(k0 + 4 * q + 1) * EE + e] * W2SCALE;
            float t2 = W2[(size_t)(k0 + 4 * q + 2) * EE + e] * W2SCALE;
            float t3 = W2[(size_t)(k0 + 4 * q + 3) * EE + e] * W2SCALE;
            int pk = __builtin_amdgcn_cvt_pk_fp8_f32(t0, t1, 0, false);
            pk     = __builtin_amdgcn_cvt_pk_fp8_f32(t2, t3, pk, true);
            dst[q] = pk;
        }
    }
}

// Fused: per-batch MLP + leave-one-out mean pooling + concat.
// grid = 2048 (one WG per batch), block = 512 (8 waves), 2 blocks/CU.
// Both GEMMs via MX-scaled K=64 f8f6f4 MFMA (fp8 e4m3, scales = 1.0).
// Phases merged: per barrier-interval produce 2 h-chunks, consume 2 (5 barriers).
__global__ __launch_bounds__(512, 4)
void fused_mlp_loo(const float* __restrict__ X,
                   const int8v* __restrict__ w1mx,       // fragment-ordered W1^T fp8 K=64 (x32)
                   const int8v* __restrict__ w2mx,       // fragment-ordered W2^T fp8 K=64 (x32)
                   const float* __restrict__ b1,
                   const float* __restrict__ b2,
                   float* __restrict__ out)
{
    __shared__ __attribute__((aligned(16))) unsigned char lds[LDS_TOT];

    const int bid = blockIdx.x;
    const int tid = threadIdx.x;
    const int w   = tid >> 6;    // wave 0..7
    const int l   = tid & 63;
    const int g5  = l >> 5;      // 0/1
    const int l31 = l & 31;
    const int wh  = w >> 1;      // GEMM1 hcol group 0..3
    const int wx  = w & 1;       // GEMM1 xrow group 0..1

    // ---- stage b1 into LDS ----
    {
        float2 v = *(const float2*)(b1 + tid * 2);
        *(float2*)(lds + BS_OFF + tid * 8) = v;
    }
    // ---- stage X (f32 -> fp8, plain padded row-major) + copy inputs to out[..., 0:256] ----
    {
        const float4* Xv = (const float4*)(X + (size_t)bid * (NN * DD));
        #pragma unroll
        for (int k = 0; k < 8; ++k) {
            int f = tid + k * 512;           // float4 index in [0,4096)
            float4 v = Xv[f];                // fully coalesced
            int row = f >> 6;                // 0..63
            int c4  = f & 63;                // float4 within row
            int pk = __builtin_amdgcn_cvt_pk_fp8_f32(v.x, v.y, 0, false);
            pk     = __builtin_amdgcn_cvt_pk_fp8_f32(v.z, v.w, pk, true);
            *(int*)(lds + XS_OFF + row * XSTRIDE + c4 * 4) = pk;
            float4* ov = (float4*)(out + (size_t)(bid * NN + row) * (DD + EE));
            ov[c4] = v;                      // input copy (exact f32)
        }
    }
    __syncthreads();

    const int xrow = 32 * wx + l31;

    f32x16 acc[2][2] = {};   // emb accumulators (scaled x32): rows 0..63 x cols [64w, 64w+64)

    // GEMM1 for chunk hc via MX K=64: c1 = 32 * h^T chunk (A = w1mx, B = Xs rows)
    auto gemm1_compute = [&](int hc, f32x16& c1) {
        const int8v* a1p = w1mx + (size_t)((hc * 4 + wh) * 4) * 64 + l;
        const unsigned char* xp0 = lds + XS_OFF + xrow * XSTRIDE + 32 * g5;
        #pragma unroll
        for (int kk = 0; kk < 4; ++kk) {
            int8v a1 = a1p[kk * 64];       // contiguous 2 KiB wave burst
            const unsigned char* xp = xp0 + kk * 64;
            int4 lo = *(const int4*)(xp);
            int4 hi = *(const int4*)(xp + 16);
            int8v xb;
            xb[0] = lo.x; xb[1] = lo.y; xb[2] = lo.z; xb[3] = lo.w;
            xb[4] = hi.x; xb[5] = hi.y; xb[6] = hi.z; xb[7] = hi.w;
            c1 = __builtin_amdgcn_mfma_scale_f32_32x32x64_f8f6f4(
                     a1, xb, c1, 0, 0, 0, 0x7F, 0, 0x7F);
        }
    };

    // bias + relu + pack h chunk into Hs ring buffer hc&3 as fp8 (padded 144B rows).
    auto pack_h = [&](int hc, const f32x16& c1) {
        unsigned char* hbase = lds + HS_OFF + (hc & 3) * HBUF + xrow * HSTRIDE;
        const float* Bs = (const float*)(lds + BS_OFF);
        const float is = 1.0f / W1SCALE;
        #pragma unroll
        for (int q = 0; q < 4; ++q) {
            float4 bb = *(const float4*)(Bs + hc * HC + 32 * wh + 4 * g5 + 8 * q);
            float v0 = fmaxf(fmaf(c1[4 * q + 0], is, bb.x), 0.f);
            float v1 = fmaxf(fmaf(c1[4 * q + 1], is, bb.y), 0.f);
            float v2 = fmaxf(fmaf(c1[4 * q + 2], is, bb.z), 0.f);
            float v3 = fmaxf(fmaf(c1[4 * q + 3], is, bb.w), 0.f);
            int pk = __builtin_amdgcn_cvt_pk_fp8_f32(v0, v1, 0, false);
            pk     = __builtin_amdgcn_cvt_pk_fp8_f32(v2, v3, pk, true);
            *(int*)(hbase + 32 * wh + 8 * q + 4 * g5) = pk;
        }
    };

    // GEMM2 chunk hc via MX K=64: acc += Hs[hc&3] @ w2mx[chunk,:], scales = 1.0
    auto gemm2_step = [&](int hc) {
        const unsigned char* hrd = lds + HS_OFF + (hc & 3) * HBUF;
        #pragma unroll
        for (int kk = 0; kk < 2; ++kk) {
            int8v a2[2];
            #pragma unroll
            for (int mf = 0; mf < 2; ++mf) {
                const unsigned char* ap = hrd + (32 * mf + l31) * HSTRIDE + kk * 64 + 32 * g5;
                int4 lo = *(const int4*)(ap);
                int4 hi = *(const int4*)(ap + 16);
                int8v a;
                a[0] = lo.x; a[1] = lo.y; a[2] = lo.z; a[3] = lo.w;
                a[4] = hi.x; a[5] = hi.y; a[6] = hi.z; a[7] = hi.w;
                a2[mf] = a;
            }
            {
                int8v bw0 = w2mx[(size_t)(((2 * w + 0) * 8 + hc) * 2 + kk) * 64 + l];
                acc[0][0] = __builtin_amdgcn_mfma_scale_f32_32x32x64_f8f6f4(
                                a2[0], bw0, acc[0][0], 0, 0, 0, 0x7F, 0, 0x7F);
                acc[1][0] = __builtin_amdgcn_mfma_scale_f32_32x32x64_f8f6f4(
                                a2[1], bw0, acc[1][0], 0, 0, 0, 0x7F, 0, 0x7F);
            }
            {
                int8v bw1 = w2mx[(size_t)(((2 * w + 1) * 8 + hc) * 2 + kk) * 64 + l];
                acc[0][1] = __builtin_amdgcn_mfma_scale_f32_32x32x64_f8f6f4(
                                a2[0], bw1, acc[0][1], 0, 0, 0, 0x7F, 0, 0x7F);
                acc[1][1] = __builtin_amdgcn_mfma_scale_f32_32x32x64_f8f6f4(
                                a2[1], bw1, acc[1][1], 0, 0, 0, 0x7F, 0, 0x7F);
            }
        }
    };

    // ---- main loop: produce-2/consume-2 per barrier-interval (5 barriers total) ----
    {
        f32x16 c1 = {};
        gemm1_compute(0, c1);
        pack_h(0, c1);
        f32x16 c1b = {};
        gemm1_compute(1, c1b);
        pack_h(1, c1b);
    }
    __syncthreads();

    #pragma unroll
    for (int i = 0; i < 3; ++i) {
        // produce chunks 2i+2, 2i+3 into ring slots (2i+2)&3, (2i+3)&3
        // (those slots held chunks 2i-2, 2i-1, consumed before the previous barrier);
        // consume chunks 2i, 2i+1. One c1 live at a time (spill discipline).
        {
            f32x16 c1 = {};
            gemm1_compute(2 * i + 2, c1);
            pack_h(2 * i + 2, c1);
        }
        gemm2_step(2 * i);
        {
            f32x16 c1 = {};
            gemm1_compute(2 * i + 3, c1);
            pack_h(2 * i + 3, c1);
        }
        gemm2_step(2 * i + 1);
        __syncthreads();
    }
    gemm2_step(6);
    gemm2_step(7);

    // ---- epilogue: in-register LOO (acc carries x32 scale from W2; undo here) ----
    float tsum[2];
    #pragma unroll
    for (int nf = 0; nf < 2; ++nf) {
        float s = 0.f;
        #pragma unroll
        for (int mf = 0; mf < 2; ++mf)
            #pragma unroll
            for (int r = 0; r < 16; ++r)
                s += acc[mf][nf][r];
        s += __shfl_xor(s, 32, 64);    // combine the two lane halves -> full 64-row column sum
        tsum[nf] = s;
    }
    const float b2c0 = b2[64 * w + l31];
    const float b2c1 = b2[64 * w + 32 + l31];
    const float sc = 1.0f / (63.0f * W2SCALE);
    float* obase = out + (size_t)bid * NN * (DD + EE) + DD;
    #pragma unroll
    for (int mf = 0; mf < 2; ++mf) {
        #pragma unroll
        for (int r = 0; r < 16; ++r) {
            int row = 32 * mf + (r & 3) + 8 * (r >> 2) + 4 * g5;
            float* orow = obase + (size_t)row * (DD + EE);
            {
                float raw = acc[mf][0][r];
                orow[64 * w + l31] = (tsum[0] - raw) * sc + b2c0;
            }
            {
                float raw = acc[mf][1][r];
                orow[64 * w + 32 + l31] = (tsum[1] - raw) * sc + b2c1;
            }
        }
    }
}

extern "C" void kernel_launch(void* const* d_in, const int* in_sizes, int n_in,
                              void* d_out, int out_size, void* d_ws, size_t ws_size,
                              hipStream_t stream) {
    const float* X  = (const float*)d_in[0];
    const float* W1 = (const float*)d_in[1];
    const float* b1 = (const float*)d_in[2];
    const float* W2 = (const float*)d_in[3];
    const float* b2 = (const float*)d_in[4];
    float* out = (float*)d_out;

    int* w1mx = (int*)d_ws;                                  // 8192 frags * 32B  = 256 KiB
    int* w2mx = w1mx + (size_t)8192 * 8;                     // 16384 frags * 32B = 512 KiB

    prep_weights<<<48, 512, 0, stream>>>(W1, W2, w1mx, w2mx);
    fused_mlp_loo<<<NB_B, 512, 0, stream>>>(X, (const int8v*)w1mx, (const int8v*)w2mx,
                                            b1, b2, out);
}

// Round 20
// 176.928 us; speedup vs baseline: 2.7248x; 2.7248x over previous
//
#include <hip/hip_runtime.h>
#include <hip/hip_bf16.h>
#include <stdint.h>

// Problem constants
#define NB_B 2048
#define NN   64
#define DD   256
#define HH   1024
#define EE   512
#define HC   128          // H chunk size
#define NCH  (HH/HC)      // 8 chunks

typedef __attribute__((ext_vector_type(16))) float f32x16;   // 32x32 MFMA accumulator
typedef __attribute__((ext_vector_type(8)))  int   int8v;    // 32B f8f6f4 operand (8 VGPRs)

#define W1SCALE 32.0f     // W1 pre-scaled into e4m3 range; undone in pack_h bias-add
#define W2SCALE 32.0f     // W2 pre-scaled into e4m3 range; undone in epilogue

// LDS layout (all-MX era):
//   Xs: [64] rows, 272B stride (256 fp8 data + 16 pad), plain row-major (17 KiB)
//   Hs: [64] rows, 144B stride (128 data + 16 pad), 2 buffers  (2 x 9216 B)
//   Bs: b1 copy, 1024 f32                                       (4 KiB)
#define XS_OFF 0
#define XSTRIDE 272
#define HS_OFF 17408
#define HSTRIDE 144
#define HBUF  9216
#define BS_OFF 35840
#define LDS_TOT 39936

// Prep: weights in per-lane K=64 MX fragment order, fp8 e4m3, 32B/lane.
//   w1mx: frag f = ((hc*4 + wh)*4 + kk)*64 + g5*32 + l31:
//       byte j (0..31) = fp8(32*W1[(kk*64 + g5*32 + j)][hc*128 + wh*32 + l31])
//       (8192 frags x 32B = 256 KiB)
//   w2mx: frag f = ((eblk*8 + hc)*2 + kk)*64 + g5*32 + l31:
//       byte j (0..31) = fp8(32*W2[(hc*128 + kk*64 + g5*32 + j)][eblk*32 + l31])
//       (16384 frags x 32B = 512 KiB)
__global__ void prep_weights(const float* __restrict__ W1, const float* __restrict__ W2,
                             int* __restrict__ w1mx, int* __restrict__ w2mx) {
    int g = blockIdx.x * 512 + threadIdx.x;      // 48 blocks * 512 = 24576 exactly
    if (g < 8192) {
        int f   = g;
        int l31 = f & 31;
        int g5  = (f >> 5) & 1;
        int kk  = (f >> 6) & 3;
        int wh  = (f >> 8) & 3;
        int hc  = f >> 10;                        // 0..7
        int h   = hc * 128 + wh * 32 + l31;
        int d0  = kk * 64 + g5 * 32;
        int* dst = w1mx + (size_t)f * 8;
        #pragma unroll
        for (int q = 0; q < 8; ++q) {
            float t0 = W1[(size_t)(d0 + 4 * q + 0) * HH + h] * W1SCALE;
            float t1 = W1[(size_t)(d0 + 4 * q + 1) * HH + h] * W1SCALE;
            float t2 = W1[(size_t)(d0 + 4 * q + 2) * HH + h] * W1SCALE;
            float t3 = W1[(size_t)(d0 + 4 * q + 3) * HH + h] * W1SCALE;
            int pk = __builtin_amdgcn_cvt_pk_fp8_f32(t0, t1, 0, false);
            pk     = __builtin_amdgcn_cvt_pk_fp8_f32(t2, t3, pk, true);
            dst[q] = pk;
        }
    } else {
        int f    = g - 8192;                      // 0..16383
        int l31  = f & 31;
        int g5   = (f >> 5) & 1;
        int kk   = (f >> 6) & 1;
        int hc   = (f >> 7) & 7;
        int eblk = f >> 10;                       // 0..15
        int e    = eblk * 32 + l31;
        int k0   = hc * 128 + kk * 64 + g5 * 32;
        int* dst = w2mx + (size_t)f * 8;
        #pragma unroll
        for (int q = 0; q < 8; ++q) {
            float t0 = W2[(size_t)(k0 + 4 * q + 0) * EE + e] * W2SCALE;
            float t1 = W2[(size_t)(k0 + 4 * q + 1) * EE + e] * W2SCALE;
            float t2 = W2[(size_t)(k0 + 4 * q + 2) * EE + e] * W2SCALE;
            float t3 = W2[(size_t)(k0 + 4 * q + 3) * EE + e] * W2SCALE;
            int pk = __builtin_amdgcn_cvt_pk_fp8_f32(t0, t1, 0, false);
            pk     = __builtin_amdgcn_cvt_pk_fp8_f32(t2, t3, pk, true);
            dst[q] = pk;
        }
    }
}

// Fused: per-batch MLP + leave-one-out mean pooling + concat.
// grid = 2048 (one WG per batch), block = 512 (8 waves), 2 blocks/CU.
// Both GEMMs via MX-scaled K=64 f8f6f4 MFMA (fp8 e4m3, scales = 1.0).
__global__ __launch_bounds__(512, 4)
void fused_mlp_loo(const float* __restrict__ X,
                   const int8v* __restrict__ w1mx,       // fragment-ordered W1^T fp8 K=64 (x32)
                   const int8v* __restrict__ w2mx,       // fragment-ordered W2^T fp8 K=64 (x32)
                   const float* __restrict__ b1,
                   const float* __restrict__ b2,
                   float* __restrict__ out)
{
    __shared__ __attribute__((aligned(16))) unsigned char lds[LDS_TOT];

    const int bid = blockIdx.x;
    const int tid = threadIdx.x;
    const int w   = tid >> 6;    // wave 0..7
    const int l   = tid & 63;
    const int g5  = l >> 5;      // 0/1
    const int l31 = l & 31;
    const int wh  = w >> 1;      // GEMM1 hcol group 0..3
    const int wx  = w & 1;       // GEMM1 xrow group 0..1

    // ---- stage b1 into LDS ----
    {
        float2 v = *(const float2*)(b1 + tid * 2);
        *(float2*)(lds + BS_OFF + tid * 8) = v;
    }
    // ---- stage X (f32 -> fp8, plain padded row-major) + copy inputs to out[..., 0:256] ----
    {
        const float4* Xv = (const float4*)(X + (size_t)bid * (NN * DD));
        #pragma unroll
        for (int k = 0; k < 8; ++k) {
            int f = tid + k * 512;           // float4 index in [0,4096)
            float4 v = Xv[f];                // fully coalesced
            int row = f >> 6;                // 0..63
            int c4  = f & 63;                // float4 within row
            int pk = __builtin_amdgcn_cvt_pk_fp8_f32(v.x, v.y, 0, false);
            pk     = __builtin_amdgcn_cvt_pk_fp8_f32(v.z, v.w, pk, true);
            *(int*)(lds + XS_OFF + row * XSTRIDE + c4 * 4) = pk;
            float4* ov = (float4*)(out + (size_t)(bid * NN + row) * (DD + EE));
            ov[c4] = v;                      // input copy (exact f32)
        }
    }
    __syncthreads();

    const int xrow = 32 * wx + l31;

    f32x16 acc[2][2] = {};   // emb accumulators (scaled x32): rows 0..63 x cols [64w, 64w+64)

    // GEMM1 for chunk hc via MX K=64: c1 = 32 * h^T chunk (A = w1mx, B = Xs rows)
    auto gemm1_compute = [&](int hc, f32x16& c1) {
        const int8v* a1p = w1mx + (size_t)((hc * 4 + wh) * 4) * 64 + l;
        const unsigned char* xp0 = lds + XS_OFF + xrow * XSTRIDE + 32 * g5;
        #pragma unroll
        for (int kk = 0; kk < 4; ++kk) {
            int8v a1 = a1p[kk * 64];       // contiguous 2 KiB wave burst
            const unsigned char* xp = xp0 + kk * 64;
            int4 lo = *(const int4*)(xp);
            int4 hi = *(const int4*)(xp + 16);
            int8v xb;
            xb[0] = lo.x; xb[1] = lo.y; xb[2] = lo.z; xb[3] = lo.w;
            xb[4] = hi.x; xb[5] = hi.y; xb[6] = hi.z; xb[7] = hi.w;
            c1 = __builtin_amdgcn_mfma_scale_f32_32x32x64_f8f6f4(
                     a1, xb, c1, 0, 0, 0, 0x7F, 0, 0x7F);
        }
    };

    // bias + relu + pack h chunk into Hs[hc&1] as fp8 (padded 144B rows).
    auto pack_h = [&](int hc, const f32x16& c1) {
        unsigned char* hbase = lds + HS_OFF + (hc & 1) * HBUF + xrow * HSTRIDE;
        const float* Bs = (const float*)(lds + BS_OFF);
        const float is = 1.0f / W1SCALE;
        #pragma unroll
        for (int q = 0; q < 4; ++q) {
            float4 bb = *(const float4*)(Bs + hc * HC + 32 * wh + 4 * g5 + 8 * q);
            float v0 = fmaxf(fmaf(c1[4 * q + 0], is, bb.x), 0.f);
            float v1 = fmaxf(fmaf(c1[4 * q + 1], is, bb.y), 0.f);
            float v2 = fmaxf(fmaf(c1[4 * q + 2], is, bb.z), 0.f);
            float v3 = fmaxf(fmaf(c1[4 * q + 3], is, bb.w), 0.f);
            int pk = __builtin_amdgcn_cvt_pk_fp8_f32(v0, v1, 0, false);
            pk     = __builtin_amdgcn_cvt_pk_fp8_f32(v2, v3, pk, true);
            *(int*)(hbase + 32 * wh + 8 * q + 4 * g5) = pk;
        }
    };

    // GEMM2 chunk hc via MX K=64: acc += Hs[hc&1] @ w2mx[chunk,:], scales = 1.0
    auto gemm2_step = [&](int hc) {
        const unsigned char* hrd = lds + HS_OFF + (hc & 1) * HBUF;
        #pragma unroll
        for (int kk = 0; kk < 2; ++kk) {
            int8v a2[2];
            #pragma unroll
            for (int mf = 0; mf < 2; ++mf) {
                const unsigned char* ap = hrd + (32 * mf + l31) * HSTRIDE + kk * 64 + 32 * g5;
                int4 lo = *(const int4*)(ap);
                int4 hi = *(const int4*)(ap + 16);
                int8v a;
                a[0] = lo.x; a[1] = lo.y; a[2] = lo.z; a[3] = lo.w;
                a[4] = hi.x; a[5] = hi.y; a[6] = hi.z; a[7] = hi.w;
                a2[mf] = a;
            }
            {
                int8v bw0 = w2mx[(size_t)(((2 * w + 0) * 8 + hc) * 2 + kk) * 64 + l];
                acc[0][0] = __builtin_amdgcn_mfma_scale_f32_32x32x64_f8f6f4(
                                a2[0], bw0, acc[0][0], 0, 0, 0, 0x7F, 0, 0x7F);
                acc[1][0] = __builtin_amdgcn_mfma_scale_f32_32x32x64_f8f6f4(
                                a2[1], bw0, acc[1][0], 0, 0, 0, 0x7F, 0, 0x7F);
            }
            {
                int8v bw1 = w2mx[(size_t)(((2 * w + 1) * 8 + hc) * 2 + kk) * 64 + l];
                acc[0][1] = __builtin_amdgcn_mfma_scale_f32_32x32x64_f8f6f4(
                                a2[0], bw1, acc[0][1], 0, 0, 0, 0x7F, 0, 0x7F);
                acc[1][1] = __builtin_amdgcn_mfma_scale_f32_32x32x64_f8f6f4(
                                a2[1], bw1, acc[1][1], 0, 0, 0, 0x7F, 0, 0x7F);
            }
        }
    };

    // ---- software-pipelined main loop: one barrier per chunk ----
    {
        f32x16 c1 = {};
        gemm1_compute(0, c1);
        pack_h(0, c1);
    }
    __syncthreads();

    for (int i = 0; i < NCH - 1; ++i) {
        // produce chunk i+1 (long-latency weight loads) interleaved with consuming chunk i
        f32x16 c1 = {};
        gemm1_compute(i + 1, c1);
        gemm2_step(i);
        pack_h(i + 1, c1);
        __syncthreads();
    }
    gemm2_step(NCH - 1);

    // ---- epilogue: in-register LOO (acc carries x32 scale from W2; undo here) ----
    float tsum[2];
    #pragma unroll
    for (int nf = 0; nf < 2; ++nf) {
        float s = 0.f;
        #pragma unroll
        for (int mf = 0; mf < 2; ++mf)
            #pragma unroll
            for (int r = 0; r < 16; ++r)
                s += acc[mf][nf][r];
        s += __shfl_xor(s, 32, 64);    // combine the two lane halves -> full 64-row column sum
        tsum[nf] = s;
    }
    const float b2c0 = b2[64 * w + l31];
    const float b2c1 = b2[64 * w + 32 + l31];
    const float sc = 1.0f / (63.0f * W2SCALE);
    float* obase = out + (size_t)bid * NN * (DD + EE) + DD;
    #pragma unroll
    for (int mf = 0; mf < 2; ++mf) {
        #pragma unroll
        for (int r = 0; r < 16; ++r) {
            int row = 32 * mf + (r & 3) + 8 * (r >> 2) + 4 * g5;
            float* orow = obase + (size_t)row * (DD + EE);
            {
                float raw = acc[mf][0][r];
                orow[64 * w + l31] = (tsum[0] - raw) * sc + b2c0;
            }
            {
                float raw = acc[mf][1][r];
                orow[64 * w + 32 + l31] = (tsum[1] - raw) * sc + b2c1;
            }
        }
    }
}

extern "C" void kernel_launch(void* const* d_in, const int* in_sizes, int n_in,
                              void* d_out, int out_size, void* d_ws, size_t ws_size,
                              hipStream_t stream) {
    const float* X  = (const float*)d_in[0];
    const float* W1 = (const float*)d_in[1];
    const float* b1 = (const float*)d_in[2];
    const float* W2 = (const float*)d_in[3];
    const float* b2 = (const float*)d_in[4];
    float* out = (float*)d_out;

    int* w1mx = (int*)d_ws;                                  // 8192 frags * 32B  = 256 KiB
    int* w2mx = w1mx + (size_t)8192 * 8;                     // 16384 frags * 32B = 512 KiB

    prep_weights<<<48, 512, 0, stream>>>(W1, W2, w1mx, w2mx);
    fused_mlp_loo<<<NB_B, 512, 0, stream>>>(X, (const int8v*)w1mx, (const int8v*)w2mx,
                                            b1, b2, out);
}

// Round 21
// 174.751 us; speedup vs baseline: 2.7588x; 1.0125x over previous
//
#include <hip/hip_runtime.h>
#include <hip/hip_bf16.h>
#include <stdint.h>

// Problem constants
#define NB_B 2048
#define NN   64
#define DD   256
#define HH   1024
#define EE   512
#define HC   128          // H chunk size
#define NCH  (HH/HC)      // 8 chunks

typedef __attribute__((ext_vector_type(16))) float f32x16;   // 32x32 MFMA accumulator
typedef __attribute__((ext_vector_type(8)))  int   int8v;    // 32B f8f6f4 operand (8 VGPRs)

#define W1SCALE 32.0f     // W1 pre-scaled into e4m3 range; undone in pack_h bias-add
#define W2SCALE 32.0f     // W2 pre-scaled into e4m3 range; undone in epilogue

// LDS layout (all-MX era):
//   Xs: [64] rows, 272B stride (256 fp8 data + 16 pad), plain row-major (17 KiB)
//   Hs: [64] rows, 144B stride (128 data + 16 pad), 2 buffers  (2 x 9216 B)
//   Bs: b1 copy, 1024 f32                                       (4 KiB)
#define XS_OFF 0
#define XSTRIDE 272
#define HS_OFF 17408
#define HSTRIDE 144
#define HBUF  9216
#define BS_OFF 35840
#define LDS_TOT 39936

// Prep: weights in per-lane K=64 MX fragment order, fp8 e4m3, 32B/lane.
//   w1mx: frag f = ((hc*4 + wh)*4 + kk)*64 + g5*32 + l31:
//       byte j (0..31) = fp8(32*W1[(kk*64 + g5*32 + j)][hc*128 + wh*32 + l31])
//       (8192 frags x 32B = 256 KiB)
//   w2mx: frag f = ((eblk*8 + hc)*2 + kk)*64 + g5*32 + l31:
//       byte j (0..31) = fp8(32*W2[(hc*128 + kk*64 + g5*32 + j)][eblk*32 + l31])
//       (16384 frags x 32B = 512 KiB)
__global__ void prep_weights(const float* __restrict__ W1, const float* __restrict__ W2,
                             int* __restrict__ w1mx, int* __restrict__ w2mx) {
    int g = blockIdx.x * 512 + threadIdx.x;      // 48 blocks * 512 = 24576 exactly
    if (g < 8192) {
        int f   = g;
        int l31 = f & 31;
        int g5  = (f >> 5) & 1;
        int kk  = (f >> 6) & 3;
        int wh  = (f >> 8) & 3;
        int hc  = f >> 10;                        // 0..7
        int h   = hc * 128 + wh * 32 + l31;
        int d0  = kk * 64 + g5 * 32;
        int* dst = w1mx + (size_t)f * 8;
        #pragma unroll
        for (int q = 0; q < 8; ++q) {
            float t0 = W1[(size_t)(d0 + 4 * q + 0) * HH + h] * W1SCALE;
            float t1 = W1[(size_t)(d0 + 4 * q + 1) * HH + h] * W1SCALE;
            float t2 = W1[(size_t)(d0 + 4 * q + 2) * HH + h] * W1SCALE;
            float t3 = W1[(size_t)(d0 + 4 * q + 3) * HH + h] * W1SCALE;
            int pk = __builtin_amdgcn_cvt_pk_fp8_f32(t0, t1, 0, false);
            pk     = __builtin_amdgcn_cvt_pk_fp8_f32(t2, t3, pk, true);
            dst[q] = pk;
        }
    } else {
        int f    = g - 8192;                      // 0..16383
        int l31  = f & 31;
        int g5   = (f >> 5) & 1;
        int kk   = (f >> 6) & 1;
        int hc   = (f >> 7) & 7;
        int eblk = f >> 10;                       // 0..15
        int e    = eblk * 32 + l31;
        int k0   = hc * 128 + kk * 64 + g5 * 32;
        int* dst = w2mx + (size_t)f * 8;
        #pragma unroll
        for (int q = 0; q < 8; ++q) {
            float t0 = W2[(size_t)(k0 + 4 * q + 0) * EE + e] * W2SCALE;
            float t1 = W2[(size_t)(k0 + 4 * q + 1) * EE + e] * W2SCALE;
            float t2 = W2[(size_t)(k0 + 4 * q + 2) * EE + e] * W2SCALE;
            float t3 = W2[(size_t)(k0 + 4 * q + 3) * EE + e] * W2SCALE;
            int pk = __builtin_amdgcn_cvt_pk_fp8_f32(t0, t1, 0, false);
            pk     = __builtin_amdgcn_cvt_pk_fp8_f32(t2, t3, pk, true);
            dst[q] = pk;
        }
    }
}

// Fused: per-batch MLP + leave-one-out mean pooling + concat.
// grid = 2048 (one WG per batch), block = 512 (8 waves), 2 blocks/CU.
// Both GEMMs via MX-scaled K=64 f8f6f4 MFMA (fp8 e4m3, scales = 1.0).
// s_setprio(1) around MFMA clusters: lets the CU scheduler favor this wave's
// matrix work over the co-resident block's load/address-calc phases.
__global__ __launch_bounds__(512, 4)
void fused_mlp_loo(const float* __restrict__ X,
                   const int8v* __restrict__ w1mx,       // fragment-ordered W1^T fp8 K=64 (x32)
                   const int8v* __restrict__ w2mx,       // fragment-ordered W2^T fp8 K=64 (x32)
                   const float* __restrict__ b1,
                   const float* __restrict__ b2,
                   float* __restrict__ out)
{
    __shared__ __attribute__((aligned(16))) unsigned char lds[LDS_TOT];

    const int bid = blockIdx.x;
    const int tid = threadIdx.x;
    const int w   = tid >> 6;    // wave 0..7
    const int l   = tid & 63;
    const int g5  = l >> 5;      // 0/1
    const int l31 = l & 31;
    const int wh  = w >> 1;      // GEMM1 hcol group 0..3
    const int wx  = w & 1;       // GEMM1 xrow group 0..1

    // ---- stage b1 into LDS ----
    {
        float2 v = *(const float2*)(b1 + tid * 2);
        *(float2*)(lds + BS_OFF + tid * 8) = v;
    }
    // ---- stage X (f32 -> fp8, plain padded row-major) + copy inputs to out[..., 0:256] ----
    {
        const float4* Xv = (const float4*)(X + (size_t)bid * (NN * DD));
        #pragma unroll
        for (int k = 0; k < 8; ++k) {
            int f = tid + k * 512;           // float4 index in [0,4096)
            float4 v = Xv[f];                // fully coalesced
            int row = f >> 6;                // 0..63
            int c4  = f & 63;                // float4 within row
            int pk = __builtin_amdgcn_cvt_pk_fp8_f32(v.x, v.y, 0, false);
            pk     = __builtin_amdgcn_cvt_pk_fp8_f32(v.z, v.w, pk, true);
            *(int*)(lds + XS_OFF + row * XSTRIDE + c4 * 4) = pk;
            float4* ov = (float4*)(out + (size_t)(bid * NN + row) * (DD + EE));
            ov[c4] = v;                      // input copy (exact f32)
        }
    }
    __syncthreads();

    const int xrow = 32 * wx + l31;

    f32x16 acc[2][2] = {};   // emb accumulators (scaled x32): rows 0..63 x cols [64w, 64w+64)

    // GEMM1 for chunk hc via MX K=64: c1 = 32 * h^T chunk (A = w1mx, B = Xs rows)
    auto gemm1_compute = [&](int hc, f32x16& c1) {
        const int8v* a1p = w1mx + (size_t)((hc * 4 + wh) * 4) * 64 + l;
        const unsigned char* xp0 = lds + XS_OFF + xrow * XSTRIDE + 32 * g5;
        __builtin_amdgcn_s_setprio(1);
        #pragma unroll
        for (int kk = 0; kk < 4; ++kk) {
            int8v a1 = a1p[kk * 64];       // contiguous 2 KiB wave burst
            const unsigned char* xp = xp0 + kk * 64;
            int4 lo = *(const int4*)(xp);
            int4 hi = *(const int4*)(xp + 16);
            int8v xb;
            xb[0] = lo.x; xb[1] = lo.y; xb[2] = lo.z; xb[3] = lo.w;
            xb[4] = hi.x; xb[5] = hi.y; xb[6] = hi.z; xb[7] = hi.w;
            c1 = __builtin_amdgcn_mfma_scale_f32_32x32x64_f8f6f4(
                     a1, xb, c1, 0, 0, 0, 0x7F, 0, 0x7F);
        }
        __builtin_amdgcn_s_setprio(0);
    };

    // bias + relu + pack h chunk into Hs[hc&1] as fp8 (padded 144B rows).
    auto pack_h = [&](int hc, const f32x16& c1) {
        unsigned char* hbase = lds + HS_OFF + (hc & 1) * HBUF + xrow * HSTRIDE;
        const float* Bs = (const float*)(lds + BS_OFF);
        const float is = 1.0f / W1SCALE;
        #pragma unroll
        for (int q = 0; q < 4; ++q) {
            float4 bb = *(const float4*)(Bs + hc * HC + 32 * wh + 4 * g5 + 8 * q);
            float v0 = fmaxf(fmaf(c1[4 * q + 0], is, bb.x), 0.f);
            float v1 = fmaxf(fmaf(c1[4 * q + 1], is, bb.y), 0.f);
            float v2 = fmaxf(fmaf(c1[4 * q + 2], is, bb.z), 0.f);
            float v3 = fmaxf(fmaf(c1[4 * q + 3], is, bb.w), 0.f);
            int pk = __builtin_amdgcn_cvt_pk_fp8_f32(v0, v1, 0, false);
            pk     = __builtin_amdgcn_cvt_pk_fp8_f32(v2, v3, pk, true);
            *(int*)(hbase + 32 * wh + 8 * q + 4 * g5) = pk;
        }
    };

    // GEMM2 chunk hc via MX K=64: acc += Hs[hc&1] @ w2mx[chunk,:], scales = 1.0
    auto gemm2_step = [&](int hc) {
        const unsigned char* hrd = lds + HS_OFF + (hc & 1) * HBUF;
        __builtin_amdgcn_s_setprio(1);
        #pragma unroll
        for (int kk = 0; kk < 2; ++kk) {
            int8v a2[2];
            #pragma unroll
            for (int mf = 0; mf < 2; ++mf) {
                const unsigned char* ap = hrd + (32 * mf + l31) * HSTRIDE + kk * 64 + 32 * g5;
                int4 lo = *(const int4*)(ap);
                int4 hi = *(const int4*)(ap + 16);
                int8v a;
                a[0] = lo.x; a[1] = lo.y; a[2] = lo.z; a[3] = lo.w;
                a[4] = hi.x; a[5] = hi.y; a[6] = hi.z; a[7] = hi.w;
                a2[mf] = a;
            }
            {
                int8v bw0 = w2mx[(size_t)(((2 * w + 0) * 8 + hc) * 2 + kk) * 64 + l];
                acc[0][0] = __builtin_amdgcn_mfma_scale_f32_32x32x64_f8f6f4(
                                a2[0], bw0, acc[0][0], 0, 0, 0, 0x7F, 0, 0x7F);
                acc[1][0] = __builtin_amdgcn_mfma_scale_f32_32x32x64_f8f6f4(
                                a2[1], bw0, acc[1][0], 0, 0, 0, 0x7F, 0, 0x7F);
            }
            {
                int8v bw1 = w2mx[(size_t)(((2 * w + 1) * 8 + hc) * 2 + kk) * 64 + l];
                acc[0][1] = __builtin_amdgcn_mfma_scale_f32_32x32x64_f8f6f4(
                                a2[0], bw1, acc[0][1], 0, 0, 0, 0x7F, 0, 0x7F);
                acc[1][1] = __builtin_amdgcn_mfma_scale_f32_32x32x64_f8f6f4(
                                a2[1], bw1, acc[1][1], 0, 0, 0, 0x7F, 0, 0x7F);
            }
        }
        __builtin_amdgcn_s_setprio(0);
    };

    // ---- software-pipelined main loop: one barrier per chunk ----
    {
        f32x16 c1 = {};
        gemm1_compute(0, c1);
        pack_h(0, c1);
    }
    __syncthreads();

    for (int i = 0; i < NCH - 1; ++i) {
        // produce chunk i+1 (long-latency weight loads) interleaved with consuming chunk i
        f32x16 c1 = {};
        gemm1_compute(i + 1, c1);
        gemm2_step(i);
        pack_h(i + 1, c1);
        __syncthreads();
    }
    gemm2_step(NCH - 1);

    // ---- epilogue: in-register LOO (acc carries x32 scale from W2; undo here) ----
    float tsum[2];
    #pragma unroll
    for (int nf = 0; nf < 2; ++nf) {
        float s = 0.f;
        #pragma unroll
        for (int mf = 0; mf < 2; ++mf)
            #pragma unroll
            for (int r = 0; r < 16; ++r)
                s += acc[mf][nf][r];
        s += __shfl_xor(s, 32, 64);    // combine the two lane halves -> full 64-row column sum
        tsum[nf] = s;
    }
    const float b2c0 = b2[64 * w + l31];
    const float b2c1 = b2[64 * w + 32 + l31];
    const float sc = 1.0f / (63.0f * W2SCALE);
    float* obase = out + (size_t)bid * NN * (DD + EE) + DD;
    #pragma unroll
    for (int mf = 0; mf < 2; ++mf) {
        #pragma unroll
        for (int r = 0; r < 16; ++r) {
            int row = 32 * mf + (r & 3) + 8 * (r >> 2) + 4 * g5;
            float* orow = obase + (size_t)row * (DD + EE);
            {
                float raw = acc[mf][0][r];
                orow[64 * w + l31] = (tsum[0] - raw) * sc + b2c0;
            }
            {
                float raw = acc[mf][1][r];
                orow[64 * w + 32 + l31] = (tsum[1] - raw) * sc + b2c1;
            }
        }
    }
}

extern "C" void kernel_launch(void* const* d_in, const int* in_sizes, int n_in,
                              void* d_out, int out_size, void* d_ws, size_t ws_size,
                              hipStream_t stream) {
    const float* X  = (const float*)d_in[0];
    const float* W1 = (const float*)d_in[1];
    const float* b1 = (const float*)d_in[2];
    const float* W2 = (const float*)d_in[3];
    const float* b2 = (const float*)d_in[4];
    float* out = (float*)d_out;

    int* w1mx = (int*)d_ws;                                  // 8192 frags * 32B  = 256 KiB
    int* w2mx = w1mx + (size_t)8192 * 8;                     // 16384 frags * 32B = 512 KiB

    prep_weights<<<48, 512, 0, stream>>>(W1, W2, w1mx, w2mx);
    fused_mlp_loo<<<NB_B, 512, 0, stream>>>(X, (const int8v*)w1mx, (const int8v*)w2mx,
                                            b1, b2, out);
}